// Round 1
// baseline (136.410 us; speedup 1.0000x reference)
//
#include <hip/hip_runtime.h>
#include <math.h>

// Problem constants (from reference setup_inputs)
namespace {
constexpr int B = 128;
constexpr int T = 2048;
constexpr int D = 128;
constexpr int P = 64;
constexpr int TOUT = T + P;          // 2112
constexpr int NC = 16;               // chunks along T
constexpr int L = T / NC;            // 128 per chunk
constexpr float ALPHA = 0.94f;
constexpr float OMA = (float)(1.0 - 0.94);   // 1-alpha
constexpr float EPS_SCALE = 1e-5f;
constexpr float UCLIP = 1e-6f;
constexpr float SQRT2 = 1.41421356237309515f;
constexpr float INV_SQRT2 = 0.70710678118654752f;
}

// ---------------------------------------------------------------------------
// Kernel A: per (b, chunk) — partial sum of x over the chunk (for the mean),
// and chunk-local EWMA scan tails of x (l1) and x^2 (l2) with zero carry-in.
// Chunk 0 uses the true init ewma[0] = in[0].
// ---------------------------------------------------------------------------
__global__ __launch_bounds__(128) void kA(const float* __restrict__ x,
                                          float* __restrict__ Spart,
                                          float* __restrict__ l1e,
                                          float* __restrict__ l2e) {
    const int c = blockIdx.x;      // chunk
    const int b = blockIdx.y;      // batch
    const int d = threadIdx.x;     // feature

    const float* xp = x + ((size_t)b * T + (size_t)c * L) * D + d;

    float x0 = xp[0];
    float sum = x0;
    float l1, l2;
    if (c == 0) { l1 = x0;        l2 = x0 * x0; }
    else        { l1 = OMA * x0;  l2 = OMA * (x0 * x0); }

    for (int k = 1; k < L; ++k) {
        float xv = xp[(size_t)k * D];
        sum += xv;
        l1 = ALPHA * l1 + OMA * xv;
        l2 = ALPHA * l2 + OMA * (xv * xv);
    }

    const size_t o = ((size_t)b * NC + c) * D + d;
    Spart[o] = sum;
    l1e[o]   = l1;
    l2e[o]   = l2;
}

// ---------------------------------------------------------------------------
// Kernel B: per (b,d) — stitch chunk carries exactly:
//   E_end[c] = l_end[c] + alpha^L * E_end[c-1]   (E_end[-1] = 0)
// carry stored for chunk c is E_end[c-1]. Also mean -> loc, and the last
// E1/E2 -> scale_future.
// ---------------------------------------------------------------------------
__global__ __launch_bounds__(256) void kB(const float* __restrict__ Spart,
                                          const float* __restrict__ l1e,
                                          const float* __restrict__ l2e,
                                          float* __restrict__ carry1,
                                          float* __restrict__ carry2,
                                          float* __restrict__ loc,
                                          float* __restrict__ scf) {
    const int tid = blockIdx.x * blockDim.x + threadIdx.x;   // b*D + d
    if (tid >= B * D) return;
    const int b = tid / D;
    const int d = tid % D;

    const float alphaL = (float)pow((double)ALPHA, (double)L);

    float sum = 0.0f, e1 = 0.0f, e2 = 0.0f;
    for (int c = 0; c < NC; ++c) {
        const size_t o = ((size_t)b * NC + c) * D + d;
        sum += Spart[o];
        carry1[o] = e1;
        carry2[o] = e2;
        e1 = l1e[o] + alphaL * e1;
        e2 = l2e[o] + alphaL * e2;
    }

    const float mu = sum * (1.0f / (float)T);
    loc[tid] = mu;
    float ew = fmaxf(e2 - 2.0f * mu * e1 + mu * mu, 0.0f);
    scf[tid] = fmaxf(sqrtf(0.5f * ew), EPS_SCALE);   // *(df-2)/df = *0.5
}

// ---------------------------------------------------------------------------
// Kernel C: per (b, chunk) — replay local scan with exact carry, compute
// scale_hist, student-t CDF (closed form for df=4), ndtri -> output.
//   u = 0.5*(1 + t*(6+t^2)/(4+t^2)^{3/2});  tail s = 0.5*(1-|r|)
//   ndtri(u) = copysign(sqrt(2)*erfcinv(2*s), r)
// ---------------------------------------------------------------------------
__global__ __launch_bounds__(128) void kC(const float* __restrict__ x,
                                          const float* __restrict__ carry1,
                                          const float* __restrict__ carry2,
                                          const float* __restrict__ loc,
                                          float* __restrict__ out) {
    const int c = blockIdx.x;
    const int b = blockIdx.y;
    const int d = threadIdx.x;

    const size_t co = ((size_t)b * NC + c) * D + d;
    const float cr1 = carry1[co];
    const float cr2 = carry2[co];
    const float mu  = loc[b * D + d];

    const float* xp = x   + ((size_t)b * T    + (size_t)c * L) * D + d;
    float*       op = out + ((size_t)b * TOUT + (size_t)c * L) * D + d;

    float l1 = 0.0f, l2 = 0.0f;
    float f = ALPHA;               // alpha^(k+1)

    for (int k = 0; k < L; ++k) {
        float xv = xp[(size_t)k * D];
        if (k == 0) {
            if (c == 0) { l1 = xv;       l2 = xv * xv; }
            else        { l1 = OMA * xv; l2 = OMA * (xv * xv); }
        } else {
            l1 = ALPHA * l1 + OMA * xv;
            l2 = ALPHA * l2 + OMA * (xv * xv);
        }
        float e1 = l1 + f * cr1;
        float e2 = l2 + f * cr2;
        f *= ALPHA;

        float ew = fmaxf(e2 - 2.0f * mu * e1 + mu * mu, 0.0f);
        float scale = fmaxf(sqrtf(0.5f * ew), EPS_SCALE);

        float tt = (xv - mu) / scale;
        float t2 = tt * tt;
        float ig = rsqrtf(4.0f + t2);
        float r  = tt * (6.0f + t2) * (ig * ig * ig);   // in [-1, 1]

        float s = 0.5f * (1.0f - fabsf(r));             // min tail prob
        s = fmaxf(s, UCLIP);                            // == clip(u, 1e-6, 1-1e-6)
        float z = copysignf(SQRT2 * erfcinvf(2.0f * s), r);

        op[(size_t)k * D] = z;
    }
}

// ---------------------------------------------------------------------------
// Kernel D: forecasts — u = clip(ndtr(z)), student-t(4) ppf closed form,
// scale/shift, write to out[:, T:, :].
// ---------------------------------------------------------------------------
__global__ __launch_bounds__(256) void kD(const float* __restrict__ zf,
                                          const float* __restrict__ loc,
                                          const float* __restrict__ scf,
                                          float* __restrict__ out) {
    const int idx = blockIdx.x * blockDim.x + threadIdx.x;
    if (idx >= B * P * D) return;
    const int d  = idx % D;
    const int bp = idx / D;
    const int p  = bp % P;
    const int b  = bp / P;

    float zv = zf[idx];
    float u = 0.5f * erfcf(-zv * INV_SQRT2);            // ndtr
    u = fminf(fmaxf(u, UCLIP), 1.0f - UCLIP);

    float a = 4.0f * u * (1.0f - u);
    a = fminf(fmaxf(a, UCLIP), 1.0f);
    float sa = sqrtf(a);
    float inner = __cosf(acosf(sa) * (1.0f / 3.0f)) / sa - 1.0f;
    // use precise cosf to be safe:
    inner = cosf(acosf(sa) * (1.0f / 3.0f)) / sa - 1.0f;
    float q = 2.0f * sqrtf(fmaxf(inner, 0.0f));

    float sgn = (u > 0.5f) ? 1.0f : ((u < 0.5f) ? -1.0f : 0.0f);
    float val = sgn * q * scf[b * D + d] + loc[b * D + d];

    out[((size_t)b * TOUT + T + p) * D + d] = val;
}

// ---------------------------------------------------------------------------
extern "C" void kernel_launch(void* const* d_in, const int* in_sizes, int n_in,
                              void* d_out, int out_size, void* d_ws, size_t ws_size,
                              hipStream_t stream) {
    const float* x  = (const float*)d_in[0];   // (B,T,D)
    const float* zf = (const float*)d_in[1];   // (B,P,D)
    float* out = (float*)d_out;                // (B,T+P,D)

    float* ws = (float*)d_ws;
    const size_t NCH = (size_t)B * NC * D;     // 262144
    float* Spart  = ws;
    float* l1e    = Spart + NCH;
    float* l2e    = l1e + NCH;
    float* carry1 = l2e + NCH;
    float* carry2 = carry1 + NCH;
    float* loc    = carry2 + NCH;              // B*D
    float* scf    = loc + (size_t)B * D;       // B*D

    kA<<<dim3(NC, B), 128, 0, stream>>>(x, Spart, l1e, l2e);
    kB<<<(B * D + 255) / 256, 256, 0, stream>>>(Spart, l1e, l2e, carry1, carry2, loc, scf);
    kC<<<dim3(NC, B), 128, 0, stream>>>(x, carry1, carry2, loc, out);
    kD<<<(B * P * D + 255) / 256, 256, 0, stream>>>(zf, loc, scf, out);
}

// Round 2
// 96.176 us; speedup vs baseline: 1.4183x; 1.4183x over previous
//
#include <hip/hip_runtime.h>
#include <math.h>

// Problem constants (from reference setup_inputs)
namespace {
constexpr int B = 128;
constexpr int T = 2048;
constexpr int D = 128;
constexpr int P = 64;
constexpr int TOUT = T + P;          // 2112
constexpr int NC = 32;               // chunks along T
constexpr int L = T / NC;            // 64 per chunk
constexpr float ALPHA = 0.94f;
constexpr float OMA = (float)(1.0 - 0.94);   // 1-alpha
constexpr float UCLIP = 1e-6f;
constexpr float SQRT2 = 1.41421356237309515f;
constexpr float INV_SQRT2 = 0.70710678118654752f;
constexpr float RMAX = 0.999998f;    // 1 - 2*UCLIP
}

// ---------------------------------------------------------------------------
// Fast erfinv (M. Giles, single precision). Central branch covers |x|<~0.9966;
// tail branch rare for ~normal data (divergence skipped via execz when no
// lane takes it).
// ---------------------------------------------------------------------------
__device__ __forceinline__ float fast_erfinv(float x) {
    float w = -__logf((1.0f - x) * (1.0f + x));
    float p;
    if (w < 5.0f) {
        w -= 2.5f;
        p = 2.81022636e-08f;
        p = fmaf(p, w, 3.43273939e-07f);
        p = fmaf(p, w, -3.5233877e-06f);
        p = fmaf(p, w, -4.39150654e-06f);
        p = fmaf(p, w, 0.00021858087f);
        p = fmaf(p, w, -0.00125372503f);
        p = fmaf(p, w, -0.00417768164f);
        p = fmaf(p, w, 0.246640727f);
        p = fmaf(p, w, 1.50140941f);
    } else {
        w = sqrtf(w) - 3.0f;
        p = -0.000200214257f;
        p = fmaf(p, w, 0.000100950558f);
        p = fmaf(p, w, 0.00134934322f);
        p = fmaf(p, w, -0.00367342844f);
        p = fmaf(p, w, 0.00573950773f);
        p = fmaf(p, w, -0.0076224613f);
        p = fmaf(p, w, 0.00943887047f);
        p = fmaf(p, w, 1.00167406f);
        p = fmaf(p, w, 2.83297682f);
    }
    return p * x;
}

// Student-t(4) CDF closed form -> ndtri, fully inlined, no divide.
// ew = E2 - 2 mu E1 + mu^2 (EWMA of (x-mu)^2, decoupled via linearity).
__device__ __forceinline__ float t_to_z(float xv, float mu, float e1, float e2) {
    float ew = fmaxf(fmaf(mu, mu, fmaf(-2.0f * mu, e1, e2)), 0.0f);
    float v = fmaxf(0.5f * ew, 1e-10f);        // (scale)^2 with eps clamp folded in
    float inv_scale = rsqrtf(v);
    float tt = (xv - mu) * inv_scale;
    float t2 = tt * tt;
    float ig = rsqrtf(4.0f + t2);
    float r = tt * (6.0f + t2) * (ig * ig * ig);   // = 2*F(t)-1 in [-1,1]
    r = fminf(fmaxf(r, -RMAX), RMAX);              // == clip(u,1e-6,1-1e-6)
    return SQRT2 * fast_erfinv(r);
}

// ---------------------------------------------------------------------------
// Kernel A: per (b, chunk) — partial sum of x (for the mean) + chunk-local
// EWMA tails of x and x^2 with zero carry-in (chunk 0 uses true init).
// ---------------------------------------------------------------------------
__global__ __launch_bounds__(128) void kA(const float* __restrict__ x,
                                          float* __restrict__ Spart,
                                          float* __restrict__ l1e,
                                          float* __restrict__ l2e) {
    const int c = blockIdx.x;      // chunk
    const int b = blockIdx.y;      // batch
    const int d = threadIdx.x;     // feature

    const float* xp = x + ((size_t)b * T + (size_t)c * L) * D + d;

    float x0 = xp[0];
    float sum = x0;
    float l1, l2;
    if (c == 0) { l1 = x0;        l2 = x0 * x0; }
    else        { l1 = OMA * x0;  l2 = OMA * (x0 * x0); }

    for (int k = 1; k < L; ++k) {
        float xv = xp[(size_t)k * D];
        sum += xv;
        l1 = ALPHA * l1 + OMA * xv;
        l2 = ALPHA * l2 + OMA * (xv * xv);
    }

    const size_t o = ((size_t)b * NC + c) * D + d;
    Spart[o] = sum;
    l1e[o]   = l1;
    l2e[o]   = l2;
}

// ---------------------------------------------------------------------------
// Kernel B: per (b,d) — stitch carries exactly. NOTE: carry1 aliases Spart,
// carry2 aliases l1e (all loads at index o happen before stores at o, same
// thread) — so NO __restrict__ here.
// ---------------------------------------------------------------------------
__global__ __launch_bounds__(256) void kB(const float* Spart,
                                          const float* l1e,
                                          const float* l2e,
                                          float* carry1,
                                          float* carry2,
                                          float* __restrict__ loc,
                                          float* __restrict__ scf) {
    const int tid = blockIdx.x * blockDim.x + threadIdx.x;   // b*D + d
    if (tid >= B * D) return;
    const int b = tid / D;
    const int d = tid % D;

    const float alphaL = (float)pow((double)ALPHA, (double)L);

    float sum = 0.0f, e1 = 0.0f, e2 = 0.0f;
    for (int c = 0; c < NC; ++c) {
        const size_t o = ((size_t)b * NC + c) * D + d;
        float sp = Spart[o];
        float t1 = l1e[o];
        float t2 = l2e[o];
        carry1[o] = e1;
        carry2[o] = e2;
        sum += sp;
        e1 = t1 + alphaL * e1;
        e2 = t2 + alphaL * e2;
    }

    const float mu = sum * (1.0f / (float)T);
    loc[tid] = mu;
    float ew = fmaxf(fmaf(mu, mu, fmaf(-2.0f * mu, e1, e2)), 0.0f);
    scf[tid] = fmaxf(sqrtf(0.5f * ew), 1e-5f);
}

// ---------------------------------------------------------------------------
// Kernel C: per (b, chunk) — replay local scan with exact carry, transform
// each element to ndtri(student_t_cdf(x)).
// ---------------------------------------------------------------------------
__global__ __launch_bounds__(128) void kC(const float* __restrict__ x,
                                          const float* __restrict__ carry1,
                                          const float* __restrict__ carry2,
                                          const float* __restrict__ loc,
                                          float* __restrict__ out) {
    const int c = blockIdx.x;
    const int b = blockIdx.y;
    const int d = threadIdx.x;

    const size_t co = ((size_t)b * NC + c) * D + d;
    const float cr1 = carry1[co];
    const float cr2 = carry2[co];
    const float mu  = loc[b * D + d];

    const float* xp = x   + ((size_t)b * T    + (size_t)c * L) * D + d;
    float*       op = out + ((size_t)b * TOUT + (size_t)c * L) * D + d;

    // k = 0
    float xv = xp[0];
    float l1, l2;
    if (c == 0) { l1 = xv;       l2 = xv * xv; }
    else        { l1 = OMA * xv; l2 = OMA * (xv * xv); }
    float f = ALPHA;                       // alpha^(k+1)
    op[0] = t_to_z(xv, mu, l1 + f * cr1, l2 + f * cr2);

    for (int k = 1; k < L; ++k) {
        xv = xp[(size_t)k * D];
        l1 = ALPHA * l1 + OMA * xv;
        l2 = ALPHA * l2 + OMA * (xv * xv);
        f *= ALPHA;
        op[(size_t)k * D] = t_to_z(xv, mu, l1 + f * cr1, l2 + f * cr2);
    }
}

// ---------------------------------------------------------------------------
// Kernel D: forecasts — u = clip(ndtr(z)), student-t(4) ppf closed form.
// ---------------------------------------------------------------------------
__global__ __launch_bounds__(256) void kD(const float* __restrict__ zf,
                                          const float* __restrict__ loc,
                                          const float* __restrict__ scf,
                                          float* __restrict__ out) {
    const int idx = blockIdx.x * blockDim.x + threadIdx.x;
    if (idx >= B * P * D) return;
    const int d  = idx % D;
    const int bp = idx / D;
    const int p  = bp % P;
    const int b  = bp / P;

    float zv = zf[idx];
    float u = 0.5f * erfcf(-zv * INV_SQRT2);            // ndtr
    u = fminf(fmaxf(u, UCLIP), 1.0f - UCLIP);

    float a = 4.0f * u * (1.0f - u);
    a = fminf(fmaxf(a, UCLIP), 1.0f);
    float sa = sqrtf(a);
    float inner = cosf(acosf(sa) * (1.0f / 3.0f)) / sa - 1.0f;
    float q = 2.0f * sqrtf(fmaxf(inner, 0.0f));

    float sgn = (u > 0.5f) ? 1.0f : ((u < 0.5f) ? -1.0f : 0.0f);
    float val = sgn * q * scf[b * D + d] + loc[b * D + d];

    out[((size_t)b * TOUT + T + p) * D + d] = val;
}

// ---------------------------------------------------------------------------
extern "C" void kernel_launch(void* const* d_in, const int* in_sizes, int n_in,
                              void* d_out, int out_size, void* d_ws, size_t ws_size,
                              hipStream_t stream) {
    const float* x  = (const float*)d_in[0];   // (B,T,D)
    const float* zf = (const float*)d_in[1];   // (B,P,D)
    float* out = (float*)d_out;                // (B,T+P,D)

    float* ws = (float*)d_ws;
    const size_t NCH = (size_t)B * NC * D;     // 524288
    float* Spart  = ws;                        // later reused as carry1
    float* l1e    = Spart + NCH;               // later reused as carry2
    float* l2e    = l1e + NCH;
    float* loc    = l2e + NCH;                 // B*D
    float* scf    = loc + (size_t)B * D;       // B*D
    float* carry1 = Spart;                     // alias (see kB)
    float* carry2 = l1e;                       // alias (see kB)

    kA<<<dim3(NC, B), 128, 0, stream>>>(x, Spart, l1e, l2e);
    kB<<<(B * D + 255) / 256, 256, 0, stream>>>(Spart, l1e, l2e, carry1, carry2, loc, scf);
    kC<<<dim3(NC, B), 128, 0, stream>>>(x, carry1, carry2, loc, out);
    kD<<<(B * P * D + 255) / 256, 256, 0, stream>>>(zf, loc, scf, out);
}